// Round 1
// baseline (1839.487 us; speedup 1.0000x reference)
//
#include <hip/hip_runtime.h>

// ---------------- problem constants ----------------
#define T_TOK 2048
#define HIDD  8192
#define NQKV  9216
#define GG    8
#define HH    16
#define DD    64
#define SS    1024
#define BB    2
#define SCALE_ATTN 0.125f   // D^-0.5

typedef __attribute__((ext_vector_type(4))) float f32x4;
typedef __attribute__((ext_vector_type(8))) short bf16x8;

#define GLOBAL_AS __attribute__((address_space(1)))
#define LDS_AS    __attribute__((address_space(3)))

__device__ __forceinline__ void glds16(const void* g, void* l) {
  __builtin_amdgcn_global_load_lds((GLOBAL_AS void*)(g), (LDS_AS void*)(l), 16, 0, 0);
}

__device__ __forceinline__ ushort f2bf(float f) {
  union { float f; unsigned u; } v; v.f = f;
  unsigned u = v.u + 0x7fffu + ((v.u >> 16) & 1u);
  return (ushort)(u >> 16);
}

// ---------------- elementwise fp32 -> bf16 ----------------
__global__ void cvt_bf16_kernel(const float* __restrict__ in, ushort* __restrict__ out, int n4) {
  int i = blockIdx.x * 256 + threadIdx.x;
  if (i >= n4) return;
  float4 v = ((const float4*)in)[i];
  ushort4 o;
  o.x = f2bf(v.x); o.y = f2bf(v.y); o.z = f2bf(v.z); o.w = f2bf(v.w);
  ((ushort4*)out)[i] = o;
}

// ---------------- f32 copy (cache init) ----------------
__global__ void copy_f32_kernel(const float* __restrict__ in, float* __restrict__ out, int n4) {
  int i = blockIdx.x * 256 + threadIdx.x;
  if (i < n4) ((float4*)out)[i] = ((const float4*)in)[i];
}

// ---------------- transpose + convert: in R x C fp32 -> out C x R bf16 ----------------
__global__ void transpose_bf16_kernel(const float* __restrict__ in, ushort* __restrict__ out,
                                      int R, int C) {
  __shared__ float tile[32][33];
  const int c0 = blockIdx.x * 32, r0 = blockIdx.y * 32;
  const int tx = threadIdx.x, ty = threadIdx.y;
  #pragma unroll
  for (int i = ty; i < 32; i += 8)
    tile[i][tx] = in[(size_t)(r0 + i) * C + (c0 + tx)];
  __syncthreads();
  #pragma unroll
  for (int i = ty; i < 32; i += 8)
    out[(size_t)(c0 + i) * R + (r0 + tx)] = f2bf(tile[tx][i]);
}

// ---------------- bf16 GEMM, B transposed: C[M,N] = A[M,K] * Bt[N,K]^T + bias[N] ----------------
// m97 structure: 128x128 tile, BK=32, 256 threads = 4 waves (2x2), 4x4 mfma 16x16x32 per wave,
// global_load_lds width-16 staging, unpadded LDS (wave-uniform base + lane*16).
__global__ __launch_bounds__(256, 2) void gemm_bt_kernel(
    const ushort* __restrict__ A, const ushort* __restrict__ Bt,
    const float* __restrict__ bias, float* __restrict__ C,
    int M, int N, int K)
{
  __shared__ __align__(16) ushort As[128 * 32];
  __shared__ __align__(16) ushort Bs[128 * 32];
  const int tid = threadIdx.x;
  const int wid = tid >> 6, lane = tid & 63;
  const int kg = lane >> 4, ln = lane & 15;
  const int m0 = blockIdx.y * 128, n0 = blockIdx.x * 128;
  const int wm = (wid >> 1) * 64, wn = (wid & 1) * 64;

  f32x4 acc[4][4] = {};

  // staging: wave wid covers tile elements [wid*1024, wid*1024+1024), 2 chunks of 512
  const int e_base = wid * 1024;
  const int e0 = e_base + lane * 8;
  const int e1 = e_base + 512 + lane * 8;
  const int r0a = e0 >> 5, c0a = e0 & 31;
  const int r1a = e1 >> 5, c1a = e1 & 31;

  const ushort* Ap0 = A + (size_t)(m0 + r0a) * K + c0a;
  const ushort* Ap1 = A + (size_t)(m0 + r1a) * K + c1a;
  const ushort* Bp0 = Bt + (size_t)(n0 + r0a) * K + c0a;
  const ushort* Bp1 = Bt + (size_t)(n0 + r1a) * K + c1a;
  ushort* lA0 = &As[e_base];
  ushort* lA1 = &As[e_base + 512];
  ushort* lB0 = &Bs[e_base];
  ushort* lB1 = &Bs[e_base + 512];

  for (int k0 = 0; k0 < K; k0 += 32) {
    glds16(Ap0 + k0, lA0);
    glds16(Ap1 + k0, lA1);
    glds16(Bp0 + k0, lB0);
    glds16(Bp1 + k0, lB1);
    __syncthreads();
    bf16x8 af[4], bfr[4];
    #pragma unroll
    for (int t = 0; t < 4; ++t) {
      af[t]  = *(const bf16x8*)&As[(wm + t * 16 + ln) * 32 + kg * 8];
      bfr[t] = *(const bf16x8*)&Bs[(wn + t * 16 + ln) * 32 + kg * 8];
    }
    #pragma unroll
    for (int i = 0; i < 4; ++i)
      #pragma unroll
      for (int j = 0; j < 4; ++j)
        acc[i][j] = __builtin_amdgcn_mfma_f32_16x16x32_bf16(af[i], bfr[j], acc[i][j], 0, 0, 0);
    __syncthreads();
  }

  // epilogue: C/D layout col=lane&15, row=(lane>>4)*4+reg
  #pragma unroll
  for (int i = 0; i < 4; ++i) {
    const int row = m0 + wm + i * 16 + kg * 4;
    #pragma unroll
    for (int j = 0; j < 4; ++j) {
      const int col = n0 + wn + j * 16 + ln;
      const float bv = bias[col];
      #pragma unroll
      for (int r = 0; r < 4; ++r)
        C[(size_t)(row + r) * N + col] = acc[i][j][r] + bv;
    }
  }
}

// ---------------- rotary + split + cache scatter ----------------
// qkv: (T, G, H+2, D) fp32. Writes Qr (T,128,64) bf16, Kr/Vr (T,8,64) bf16,
// cache (2,4096,8,64) fp32 at slots.
__global__ void rotary_scatter_kernel(const float* __restrict__ qkv,
                                      const float* __restrict__ cosb, const float* __restrict__ sinb,
                                      const int* __restrict__ slots,
                                      ushort* __restrict__ Qr, ushort* __restrict__ Kr,
                                      ushort* __restrict__ Vr, float* __restrict__ cache)
{
  const int t = blockIdx.x;
  const int slot = slots[t];
  for (int j = threadIdx.x; j < GG * 18 * 32; j += 256) {
    const int g = j / 576;
    const int rem = j - g * 576;
    const int head = rem >> 5;
    const int d = rem & 31;
    const float* row = qkv + (size_t)t * NQKV + g * 1152 + head * 64;
    const float x1 = row[d], x2 = row[d + 32];
    const float c = cosb[t * 32 + d], s = sinb[t * 32 + d];
    if (head < 16) {
      const size_t o = ((size_t)t * 128 + g * 16 + head) * 64;
      Qr[o + d]      = f2bf(x1 * c - x2 * s);
      Qr[o + 32 + d] = f2bf(x2 * c + x1 * s);
    } else if (head == 16) {
      const float o1 = x1 * c - x2 * s, o2 = x2 * c + x1 * s;
      const size_t o = ((size_t)t * GG + g) * 64;
      Kr[o + d] = f2bf(o1); Kr[o + 32 + d] = f2bf(o2);
      const size_t co = ((size_t)slot * GG + g) * 64;
      cache[co + d] = o1; cache[co + 32 + d] = o2;
    } else {
      const size_t o = ((size_t)t * GG + g) * 64;
      Vr[o + d] = f2bf(x1); Vr[o + 32 + d] = f2bf(x2);
      const size_t co = (size_t)4096 * GG * 64 + ((size_t)slot * GG + g) * 64;
      cache[co + d] = x1; cache[co + 32 + d] = x2;
    }
  }
}

// ---------------- flash attention (causal, GQA) ----------------
// grid (16 qblocks, 128 gh, 2 b), 256 threads = 4 waves. Each wave owns 16 q rows.
// Per iter: stage K tile [t][d] (pad 72) + V^T tile [d][t] (pad 72); QK^T by MFMA;
// online softmax (16-lane shuffle reduce); P via LDS C->A layout round-trip; PV by MFMA.
__global__ __launch_bounds__(256, 2) void flash_attn_kernel(
    const ushort* __restrict__ Q, const ushort* __restrict__ Kc,
    const ushort* __restrict__ Vc, ushort* __restrict__ O)
{
  const int qb = blockIdx.x;
  const int gh = blockIdx.y;
  const int g  = gh >> 4;
  const int b  = blockIdx.z;
  const int tid = threadIdx.x;
  const int wid = tid >> 6, lane = tid & 63;
  const int kg = lane >> 4, ln = lane & 15;

  __shared__ __align__(16) ushort Ks[64 * 72];
  __shared__ __align__(16) ushort Vt[64 * 72];
  __shared__ __align__(16) ushort Ps[64 * 72];

  // Q A-frags: A[m=ln][k=kg*8+j], rows = this wave's 16 q rows
  const int sq = qb * 64 + wid * 16 + ln;
  const size_t qoff = ((size_t)(b * SS + sq) * 128 + gh) * 64;
  const bf16x8 qf0 = *(const bf16x8*)&Q[qoff + kg * 8];
  const bf16x8 qf1 = *(const bf16x8*)&Q[qoff + 32 + kg * 8];

  f32x4 acc_o[4] = {};
  float m_i[4], l_i[4];
  #pragma unroll
  for (int r = 0; r < 4; ++r) { m_i[r] = -1e30f; l_i[r] = 0.f; }

  const int srow = qb * 64 + wid * 16 + kg * 4;   // C-layout base row (seq pos)

  for (int it = 0; it <= qb; ++it) {
    const int t0 = it * 64;
    __syncthreads();   // prior iter's LDS reads done before restage
    #pragma unroll
    for (int rep = 0; rep < 2; ++rep) {
      const int u = rep * 256 + tid;
      const int tt = u >> 3;
      const int d0 = (u & 7) * 8;
      const size_t src = ((size_t)(b * SS + t0 + tt) * GG + g) * 64 + d0;
      *(uint4*)&Ks[tt * 72 + d0] = *(const uint4*)&Kc[src];
      bf16x8 vv = *(const bf16x8*)&Vc[src];
      #pragma unroll
      for (int jj = 0; jj < 8; ++jj)
        Vt[(d0 + jj) * 72 + tt] = ((const ushort*)&vv)[jj];
    }
    __syncthreads();

    // scores: 4 t-tiles of 16, K over D in 2 chunks of 32
    f32x4 sc[4];
    #pragma unroll
    for (int tt = 0; tt < 4; ++tt) {
      bf16x8 kf0 = *(const bf16x8*)&Ks[(tt * 16 + ln) * 72 + kg * 8];
      bf16x8 kf1 = *(const bf16x8*)&Ks[(tt * 16 + ln) * 72 + 32 + kg * 8];
      f32x4 z = {};
      z = __builtin_amdgcn_mfma_f32_16x16x32_bf16(qf0, kf0, z, 0, 0, 0);
      z = __builtin_amdgcn_mfma_f32_16x16x32_bf16(qf1, kf1, z, 0, 0, 0);
      sc[tt] = z;
    }

    if (it == qb) {   // diagonal block: causal mask
      #pragma unroll
      for (int tt = 0; tt < 4; ++tt) {
        const int tg = t0 + tt * 16 + ln;
        #pragma unroll
        for (int r = 0; r < 4; ++r)
          sc[tt][r] = (tg <= srow + r) ? sc[tt][r] * SCALE_ATTN : -1e30f;
      }
    } else {
      #pragma unroll
      for (int tt = 0; tt < 4; ++tt)
        #pragma unroll
        for (int r = 0; r < 4; ++r)
          sc[tt][r] *= SCALE_ATTN;
    }

    // online softmax, rows live across lanes (row=(kg*4+r), cols spread over 16 lanes x 4 tiles)
    float alpha[4];
    #pragma unroll
    for (int r = 0; r < 4; ++r) {
      float mx = fmaxf(fmaxf(sc[0][r], sc[1][r]), fmaxf(sc[2][r], sc[3][r]));
      #pragma unroll
      for (int off = 1; off < 16; off <<= 1)
        mx = fmaxf(mx, __shfl_xor(mx, off, 64));
      const float mn = fmaxf(m_i[r], mx);
      float rs = 0.f;
      #pragma unroll
      for (int tt = 0; tt < 4; ++tt) {
        const float p = __expf(sc[tt][r] - mn);
        sc[tt][r] = p; rs += p;
      }
      #pragma unroll
      for (int off = 1; off < 16; off <<= 1)
        rs += __shfl_xor(rs, off, 64);
      alpha[r] = __expf(m_i[r] - mn);
      l_i[r] = l_i[r] * alpha[r] + rs;
      m_i[r] = mn;
    }
    #pragma unroll
    for (int dt = 0; dt < 4; ++dt)
      #pragma unroll
      for (int r = 0; r < 4; ++r)
        acc_o[dt][r] *= alpha[r];

    // P: C-layout -> LDS [q][t] (each wave writes only its own 16-row strip)
    #pragma unroll
    for (int tt = 0; tt < 4; ++tt)
      #pragma unroll
      for (int r = 0; r < 4; ++r)
        Ps[(wid * 16 + kg * 4 + r) * 72 + tt * 16 + ln] = f2bf(sc[tt][r]);
    __syncthreads();

    // PV: P as A-frag (k=t chunks of 32), V^T as B-frag (n=d)
    #pragma unroll
    for (int c = 0; c < 2; ++c) {
      bf16x8 pf = *(const bf16x8*)&Ps[(wid * 16 + ln) * 72 + c * 32 + kg * 8];
      #pragma unroll
      for (int dt = 0; dt < 4; ++dt) {
        bf16x8 vf = *(const bf16x8*)&Vt[(dt * 16 + ln) * 72 + c * 32 + kg * 8];
        acc_o[dt] = __builtin_amdgcn_mfma_f32_16x16x32_bf16(pf, vf, acc_o[dt], 0, 0, 0);
      }
    }
  }

  // epilogue: O[(b,s,gh,d)] bf16
  #pragma unroll
  for (int dt = 0; dt < 4; ++dt) {
    #pragma unroll
    for (int r = 0; r < 4; ++r) {
      const float o = acc_o[dt][r] / l_i[r];
      O[((size_t)(b * SS + srow + r) * 128 + gh) * 64 + dt * 16 + ln] = f2bf(o);
    }
  }
}

// ---------------- workspace layout (bytes) ----------------
#define WS0_HB   ((size_t)0)                       // hidden bf16 (33.5MB), later attn bf16
#define WS1_WT   ((size_t)33554432)                // wT: w_qkvT (151MB) then w_denseT (134MB)
#define WS2_QKV  ((size_t)(33554432 + 150994944))  // qkv fp32 (75.5MB)
#define WS3_QR   (WS2_QKV + (size_t)75497472)      // q_rot bf16 (33.5MB)
#define WS4_KR   (WS3_QR + (size_t)33554432)       // k_rot bf16 (2MB)
#define WS5_VR   (WS4_KR + (size_t)2097152)        // v bf16 (2MB)

extern "C" void kernel_launch(void* const* d_in, const int* in_sizes, int n_in,
                              void* d_out, int out_size, void* d_ws, size_t ws_size,
                              hipStream_t stream) {
  const float* hidden  = (const float*)d_in[0];
  const float* cosb    = (const float*)d_in[1];
  const float* sinb    = (const float*)d_in[2];
  const float* w_qkv   = (const float*)d_in[3];
  const float* b_qkv   = (const float*)d_in[4];
  const float* w_dense = (const float*)d_in[5];
  const float* b_dense = (const float*)d_in[6];
  const float* kv_in   = (const float*)d_in[7];
  const int*   slots   = (const int*)d_in[8];

  float* out = (float*)d_out;
  float* out_cache = out + (size_t)T_TOK * HIDD;

  char* ws = (char*)d_ws;
  ushort* hb   = (ushort*)(ws + WS0_HB);
  ushort* wT   = (ushort*)(ws + WS1_WT);
  float*  qkv  = (float*)(ws + WS2_QKV);
  ushort* qr   = (ushort*)(ws + WS3_QR);
  ushort* kr   = (ushort*)(ws + WS4_KR);
  ushort* vr   = (ushort*)(ws + WS5_VR);
  ushort* attn = hb;  // reuse: hidden_bf16 dead after GEMM1

  // 1. hidden -> bf16
  cvt_bf16_kernel<<<(T_TOK * HIDD / 4 + 255) / 256, 256, 0, stream>>>(hidden, hb, T_TOK * HIDD / 4);
  // 2. w_qkv (HID x NQKV) -> wT (NQKV x HID) bf16
  transpose_bf16_kernel<<<dim3(NQKV / 32, HIDD / 32), dim3(32, 8), 0, stream>>>(w_qkv, wT, HIDD, NQKV);
  // 3. qkv = hb @ wT^T + b_qkv   (M=2048, N=9216, K=8192)
  gemm_bt_kernel<<<dim3(NQKV / 128, T_TOK / 128), 256, 0, stream>>>(hb, wT, b_qkv, qkv, T_TOK, NQKV, HIDD);
  // 4. cache init = input kv_cache
  copy_f32_kernel<<<(2 * 4096 * GG * DD / 4 + 255) / 256, 256, 0, stream>>>(kv_in, out_cache, 2 * 4096 * GG * DD / 4);
  // 5. rotary + split + cache scatter
  rotary_scatter_kernel<<<T_TOK, 256, 0, stream>>>(qkv, cosb, sinb, slots, qr, kr, vr, out_cache);
  // 6. w_dense (HID x HID) -> wT (reuse; after GEMM1 by stream order)
  transpose_bf16_kernel<<<dim3(HIDD / 32, HIDD / 32), dim3(32, 8), 0, stream>>>(w_dense, wT, HIDD, HIDD);
  // 7. flash attention -> attn bf16 (T, 8192)
  flash_attn_kernel<<<dim3(SS / 64, GG * HH, BB), 256, 0, stream>>>(qr, kr, vr, attn);
  // 8. out = attn @ wT^T + b_dense   (M=2048, N=8192, K=8192)
  gemm_bt_kernel<<<dim3(HIDD / 128, T_TOK / 128), 256, 0, stream>>>(attn, wT, b_dense, out, T_TOK, HIDD, HIDD);
}

// Round 2
// 1787.690 us; speedup vs baseline: 1.0290x; 1.0290x over previous
//
#include <hip/hip_runtime.h>

// ---------------- problem constants ----------------
#define T_TOK 2048
#define HIDD  8192
#define NQKV  9216
#define GG    8
#define HH    16
#define DD    64
#define SS    1024
#define BB    2
#define SCALE_ATTN 0.125f   // D^-0.5

typedef __attribute__((ext_vector_type(4))) float f32x4;
typedef __attribute__((ext_vector_type(8))) short bf16x8;

#define GLOBAL_AS __attribute__((address_space(1)))
#define LDS_AS    __attribute__((address_space(3)))

__device__ __forceinline__ void glds16(const void* g, void* l) {
  __builtin_amdgcn_global_load_lds((GLOBAL_AS void*)(g), (LDS_AS void*)(l), 16, 0, 0);
}

__device__ __forceinline__ ushort f2bf(float f) {
  union { float f; unsigned u; } v; v.f = f;
  unsigned u = v.u + 0x7fffu + ((v.u >> 16) & 1u);
  return (ushort)(u >> 16);
}

// ---------------- elementwise fp32 -> bf16 ----------------
__global__ void cvt_bf16_kernel(const float* __restrict__ in, ushort* __restrict__ out, int n4) {
  int i = blockIdx.x * 256 + threadIdx.x;
  if (i >= n4) return;
  float4 v = ((const float4*)in)[i];
  ushort4 o;
  o.x = f2bf(v.x); o.y = f2bf(v.y); o.z = f2bf(v.z); o.w = f2bf(v.w);
  ((ushort4*)out)[i] = o;
}

// ---------------- f32 copy (cache init) ----------------
__global__ void copy_f32_kernel(const float* __restrict__ in, float* __restrict__ out, int n4) {
  int i = blockIdx.x * 256 + threadIdx.x;
  if (i < n4) ((float4*)out)[i] = ((const float4*)in)[i];
}

// ---------------- transpose + convert v2: in R x C fp32 -> out C x R bf16 ----------------
// 64x64 tile, float4 staged loads, ushort4 coalesced stores, pad-65 LDS (2-way free).
__global__ __launch_bounds__(256) void transpose_bf16_kernel(
    const float* __restrict__ in, ushort* __restrict__ out, int R, int C)
{
  __shared__ float tile[64][65];
  const int c0 = blockIdx.x * 64, r0 = blockIdx.y * 64;
  const int tid = threadIdx.x;
  const int tx = tid & 15, iy = tid >> 4;     // stage: 16 float4-cols x 16 rows/pass
  #pragma unroll
  for (int p = 0; p < 4; ++p) {
    const int i = iy + p * 16;
    const float4 v = *(const float4*)&in[(size_t)(r0 + i) * C + c0 + tx * 4];
    tile[i][tx * 4 + 0] = v.x; tile[i][tx * 4 + 1] = v.y;
    tile[i][tx * 4 + 2] = v.z; tile[i][tx * 4 + 3] = v.w;
  }
  __syncthreads();
  const int r4 = tid & 15, cg = tid >> 4;     // write: lanes contiguous in r
  #pragma unroll
  for (int p = 0; p < 4; ++p) {
    const int c = cg + p * 16;
    ushort4 o;
    o.x = f2bf(tile[r4 * 4 + 0][c]);
    o.y = f2bf(tile[r4 * 4 + 1][c]);
    o.z = f2bf(tile[r4 * 4 + 2][c]);
    o.w = f2bf(tile[r4 * 4 + 3][c]);
    *(ushort4*)&out[(size_t)(c0 + c) * R + r0 + r4 * 4] = o;
  }
}

// ---------------- bf16 GEMM, B transposed: C[M,N] = A[M,K] * Bt[N,K]^T + bias[N] ----------------
__global__ __launch_bounds__(256, 2) void gemm_bt_kernel(
    const ushort* __restrict__ A, const ushort* __restrict__ Bt,
    const float* __restrict__ bias, float* __restrict__ C,
    int M, int N, int K)
{
  __shared__ __align__(16) ushort As[128 * 32];
  __shared__ __align__(16) ushort Bs[128 * 32];
  const int tid = threadIdx.x;
  const int wid = tid >> 6, lane = tid & 63;
  const int kg = lane >> 4, ln = lane & 15;
  const int m0 = blockIdx.y * 128, n0 = blockIdx.x * 128;
  const int wm = (wid >> 1) * 64, wn = (wid & 1) * 64;

  f32x4 acc[4][4] = {};

  const int e_base = wid * 1024;
  const int e0 = e_base + lane * 8;
  const int e1 = e_base + 512 + lane * 8;
  const int r0a = e0 >> 5, c0a = e0 & 31;
  const int r1a = e1 >> 5, c1a = e1 & 31;

  const ushort* Ap0 = A + (size_t)(m0 + r0a) * K + c0a;
  const ushort* Ap1 = A + (size_t)(m0 + r1a) * K + c1a;
  const ushort* Bp0 = Bt + (size_t)(n0 + r0a) * K + c0a;
  const ushort* Bp1 = Bt + (size_t)(n0 + r1a) * K + c1a;
  ushort* lA0 = &As[e_base];
  ushort* lA1 = &As[e_base + 512];
  ushort* lB0 = &Bs[e_base];
  ushort* lB1 = &Bs[e_base + 512];

  for (int k0 = 0; k0 < K; k0 += 32) {
    glds16(Ap0 + k0, lA0);
    glds16(Ap1 + k0, lA1);
    glds16(Bp0 + k0, lB0);
    glds16(Bp1 + k0, lB1);
    __syncthreads();
    bf16x8 af[4], bfr[4];
    #pragma unroll
    for (int t = 0; t < 4; ++t) {
      af[t]  = *(const bf16x8*)&As[(wm + t * 16 + ln) * 32 + kg * 8];
      bfr[t] = *(const bf16x8*)&Bs[(wn + t * 16 + ln) * 32 + kg * 8];
    }
    #pragma unroll
    for (int i = 0; i < 4; ++i)
      #pragma unroll
      for (int j = 0; j < 4; ++j)
        acc[i][j] = __builtin_amdgcn_mfma_f32_16x16x32_bf16(af[i], bfr[j], acc[i][j], 0, 0, 0);
    __syncthreads();
  }

  #pragma unroll
  for (int i = 0; i < 4; ++i) {
    const int row = m0 + wm + i * 16 + kg * 4;
    #pragma unroll
    for (int j = 0; j < 4; ++j) {
      const int col = n0 + wn + j * 16 + ln;
      const float bv = bias[col];
      #pragma unroll
      for (int r = 0; r < 4; ++r)
        C[(size_t)(row + r) * N + col] = acc[i][j][r] + bv;
    }
  }
}

// ---------------- rotary + split + cache scatter ----------------
// qkv: (T, G, H+2, D) fp32.
// Writes: Qr (b, gh, s, d) bf16; Kr (b, g, s, d) bf16; Vr (b, g, d, s) bf16 (pre-transposed);
// cache (2, 4096, G, D) fp32 at slots.
__global__ void rotary_scatter_kernel(const float* __restrict__ qkv,
                                      const float* __restrict__ cosb, const float* __restrict__ sinb,
                                      const int* __restrict__ slots,
                                      ushort* __restrict__ Qr, ushort* __restrict__ Kr,
                                      ushort* __restrict__ Vr, float* __restrict__ cache)
{
  const int t = blockIdx.x;
  const int b = t >> 10, s = t & 1023;
  const int slot = slots[t];
  for (int j = threadIdx.x; j < GG * 18 * 32; j += 256) {
    const int g = j / 576;
    const int rem = j - g * 576;
    const int head = rem >> 5;
    const int d = rem & 31;
    const float* row = qkv + (size_t)t * NQKV + g * 1152 + head * 64;
    const float x1 = row[d], x2 = row[d + 32];
    const float c = cosb[t * 32 + d], s_ = sinb[t * 32 + d];
    if (head < 16) {
      const size_t o = ((size_t)((b * 128 + g * 16 + head) * 1024 + s)) * 64;
      Qr[o + d]      = f2bf(x1 * c - x2 * s_);
      Qr[o + 32 + d] = f2bf(x2 * c + x1 * s_);
    } else if (head == 16) {
      const float o1 = x1 * c - x2 * s_, o2 = x2 * c + x1 * s_;
      const size_t o = ((size_t)((b * 8 + g) * 1024 + s)) * 64;
      Kr[o + d] = f2bf(o1); Kr[o + 32 + d] = f2bf(o2);
      const size_t co = ((size_t)slot * GG + g) * 64;
      cache[co + d] = o1; cache[co + 32 + d] = o2;
    } else {
      const size_t vo = ((size_t)((b * 8 + g) * 64 + d)) * 1024 + s;
      Vr[vo] = f2bf(x1);
      Vr[vo + (size_t)32 * 1024] = f2bf(x2);
      const size_t co = (size_t)4096 * GG * 64 + ((size_t)slot * GG + g) * 64;
      cache[co + d] = x1; cache[co + 32 + d] = x2;
    }
  }
}

// ---------------- flash attention v2 (causal, GQA) ----------------
// grid (8 qblocks of 128 rows, 128 gh, 2 b), 256 threads = 4 waves.
// Each wave owns 2 strips of 16 q rows (rows wid*32 .. wid*32+31).
// Per 64-col KV tile: coalesced uint4 staging of K (b,g,s,d) and V^T (b,g,d,s);
// QK^T by MFMA; online softmax; P via LDS C->A round trip; PV by MFMA.
__global__ __launch_bounds__(256, 4) void flash_attn_kernel(
    const ushort* __restrict__ Q, const ushort* __restrict__ Kc,
    const ushort* __restrict__ Vc, ushort* __restrict__ O)
{
  const int qb = blockIdx.x;
  const int gh = blockIdx.y;
  const int g  = gh >> 4;
  const int b  = blockIdx.z;
  const int tid = threadIdx.x;
  const int wid = tid >> 6, lane = tid & 63;
  const int kg = lane >> 4, ln = lane & 15;

  __shared__ __align__(16) ushort Ks[64 * 72];   // [t][d] pad 72
  __shared__ __align__(16) ushort Vt[64 * 72];   // [d][t] pad 72
  __shared__ __align__(16) ushort Ps[128 * 72];  // [q][t] pad 72

  // Q A-frags: 2 strips x 2 k-chunks
  bf16x8 qf[2][2];
  #pragma unroll
  for (int st = 0; st < 2; ++st) {
    const int sq = qb * 128 + wid * 32 + st * 16 + ln;
    const size_t qoff = ((size_t)((b * 128 + gh) * 1024 + sq)) * 64;
    qf[st][0] = *(const bf16x8*)&Q[qoff + kg * 8];
    qf[st][1] = *(const bf16x8*)&Q[qoff + 32 + kg * 8];
  }

  f32x4 acc_o[2][4] = {};
  float m_i[2][4], l_i[2][4];
  #pragma unroll
  for (int st = 0; st < 2; ++st)
    #pragma unroll
    for (int r = 0; r < 4; ++r) { m_i[st][r] = -1e30f; l_i[st][r] = 0.f; }

  const size_t kbase = ((size_t)(b * 8 + g) * 1024) * 64;   // K (b,g,s,d)
  const size_t vbase = ((size_t)(b * 8 + g) * 64) * 1024;   // V (b,g,d,s)

  const int n_it = 2 * qb + 2;
  for (int it = 0; it < n_it; ++it) {
    const int t0 = it * 64;
    __syncthreads();   // prior iter's LDS reads done before restage
    #pragma unroll
    for (int rep = 0; rep < 2; ++rep) {
      const int idx = rep * 256 + tid;
      const int rr = idx >> 3, c8 = (idx & 7) * 8;
      *(uint4*)&Ks[rr * 72 + c8] = *(const uint4*)&Kc[kbase + (size_t)(t0 + rr) * 64 + c8];
      *(uint4*)&Vt[rr * 72 + c8] = *(const uint4*)&Vc[vbase + (size_t)rr * 1024 + t0 + c8];
    }
    __syncthreads();

    // scores
    f32x4 sc[2][4];
    #pragma unroll
    for (int tt = 0; tt < 4; ++tt) {
      const bf16x8 kf0 = *(const bf16x8*)&Ks[(tt * 16 + ln) * 72 + kg * 8];
      const bf16x8 kf1 = *(const bf16x8*)&Ks[(tt * 16 + ln) * 72 + 32 + kg * 8];
      #pragma unroll
      for (int st = 0; st < 2; ++st) {
        f32x4 z = {};
        z = __builtin_amdgcn_mfma_f32_16x16x32_bf16(qf[st][0], kf0, z, 0, 0, 0);
        z = __builtin_amdgcn_mfma_f32_16x16x32_bf16(qf[st][1], kf1, z, 0, 0, 0);
        sc[st][tt] = z;
      }
    }

    if (it >= 2 * qb) {   // tiles overlapping the diagonal: causal mask
      #pragma unroll
      for (int st = 0; st < 2; ++st) {
        const int srow = qb * 128 + wid * 32 + st * 16 + kg * 4;
        #pragma unroll
        for (int tt = 0; tt < 4; ++tt) {
          const int tg = t0 + tt * 16 + ln;
          #pragma unroll
          for (int r = 0; r < 4; ++r)
            sc[st][tt][r] = (tg <= srow + r) ? sc[st][tt][r] * SCALE_ATTN : -1e30f;
        }
      }
    } else {
      #pragma unroll
      for (int st = 0; st < 2; ++st)
        #pragma unroll
        for (int tt = 0; tt < 4; ++tt)
          #pragma unroll
          for (int r = 0; r < 4; ++r)
            sc[st][tt][r] *= SCALE_ATTN;
    }

    // online softmax (rows = st x r; cols spread over 16 lanes x 4 tiles)
    #pragma unroll
    for (int st = 0; st < 2; ++st) {
      float alpha[4];
      #pragma unroll
      for (int r = 0; r < 4; ++r) {
        float mx = fmaxf(fmaxf(sc[st][0][r], sc[st][1][r]), fmaxf(sc[st][2][r], sc[st][3][r]));
        #pragma unroll
        for (int off = 1; off < 16; off <<= 1)
          mx = fmaxf(mx, __shfl_xor(mx, off, 64));
        const float mn = fmaxf(m_i[st][r], mx);
        float rs = 0.f;
        #pragma unroll
        for (int tt = 0; tt < 4; ++tt) {
          const float p = __expf(sc[st][tt][r] - mn);
          sc[st][tt][r] = p; rs += p;
        }
        #pragma unroll
        for (int off = 1; off < 16; off <<= 1)
          rs += __shfl_xor(rs, off, 64);
        alpha[r] = __expf(m_i[st][r] - mn);
        l_i[st][r] = l_i[st][r] * alpha[r] + rs;
        m_i[st][r] = mn;
      }
      #pragma unroll
      for (int dt = 0; dt < 4; ++dt)
        #pragma unroll
        for (int r = 0; r < 4; ++r)
          acc_o[st][dt][r] *= alpha[r];
      // P: C-layout -> LDS [q][t]
      #pragma unroll
      for (int tt = 0; tt < 4; ++tt)
        #pragma unroll
        for (int r = 0; r < 4; ++r)
          Ps[(wid * 32 + st * 16 + kg * 4 + r) * 72 + tt * 16 + ln] = f2bf(sc[st][tt][r]);
    }
    __syncthreads();

    // PV: P as A-frag, V^T as B-frag
    #pragma unroll
    for (int c = 0; c < 2; ++c) {
      bf16x8 vf[4];
      #pragma unroll
      for (int dt = 0; dt < 4; ++dt)
        vf[dt] = *(const bf16x8*)&Vt[(dt * 16 + ln) * 72 + c * 32 + kg * 8];
      #pragma unroll
      for (int st = 0; st < 2; ++st) {
        const bf16x8 pf = *(const bf16x8*)&Ps[(wid * 32 + st * 16 + ln) * 72 + c * 32 + kg * 8];
        #pragma unroll
        for (int dt = 0; dt < 4; ++dt)
          acc_o[st][dt] = __builtin_amdgcn_mfma_f32_16x16x32_bf16(pf, vf[dt], acc_o[st][dt], 0, 0, 0);
      }
    }
  }

  // epilogue: attn (t, gh*64+d) bf16 for GEMM2
  #pragma unroll
  for (int st = 0; st < 2; ++st) {
    const int srow = qb * 128 + wid * 32 + st * 16 + kg * 4;
    #pragma unroll
    for (int dt = 0; dt < 4; ++dt) {
      #pragma unroll
      for (int r = 0; r < 4; ++r) {
        const float o = acc_o[st][dt][r] / l_i[st][r];
        O[((size_t)(b * 1024 + srow + r)) * 8192 + gh * 64 + dt * 16 + ln] = f2bf(o);
      }
    }
  }
}

// ---------------- workspace layout (bytes) ----------------
#define WS0_HB   ((size_t)0)                       // hidden bf16 (33.5MB), later attn bf16
#define WS1_WT   ((size_t)33554432)                // wT: w_qkvT (151MB) then w_denseT (134MB)
#define WS2_QKV  ((size_t)(33554432 + 150994944))  // qkv fp32 (75.5MB)
#define WS3_QR   (WS2_QKV + (size_t)75497472)      // q_rot bf16 (33.5MB)
#define WS4_KR   (WS3_QR + (size_t)33554432)       // k_rot bf16 (2MB)
#define WS5_VR   (WS4_KR + (size_t)2097152)        // v^T bf16 (2MB)

extern "C" void kernel_launch(void* const* d_in, const int* in_sizes, int n_in,
                              void* d_out, int out_size, void* d_ws, size_t ws_size,
                              hipStream_t stream) {
  const float* hidden  = (const float*)d_in[0];
  const float* cosb    = (const float*)d_in[1];
  const float* sinb    = (const float*)d_in[2];
  const float* w_qkv   = (const float*)d_in[3];
  const float* b_qkv   = (const float*)d_in[4];
  const float* w_dense = (const float*)d_in[5];
  const float* b_dense = (const float*)d_in[6];
  const float* kv_in   = (const float*)d_in[7];
  const int*   slots   = (const int*)d_in[8];

  float* out = (float*)d_out;
  float* out_cache = out + (size_t)T_TOK * HIDD;

  char* ws = (char*)d_ws;
  ushort* hb   = (ushort*)(ws + WS0_HB);
  ushort* wT   = (ushort*)(ws + WS1_WT);
  float*  qkv  = (float*)(ws + WS2_QKV);
  ushort* qr   = (ushort*)(ws + WS3_QR);
  ushort* kr   = (ushort*)(ws + WS4_KR);
  ushort* vr   = (ushort*)(ws + WS5_VR);
  ushort* attn = hb;  // reuse: hidden_bf16 dead after GEMM1

  // 1. hidden -> bf16
  cvt_bf16_kernel<<<(T_TOK * HIDD / 4 + 255) / 256, 256, 0, stream>>>(hidden, hb, T_TOK * HIDD / 4);
  // 2. w_qkv (HID x NQKV) -> wT (NQKV x HID) bf16
  transpose_bf16_kernel<<<dim3(NQKV / 64, HIDD / 64), 256, 0, stream>>>(w_qkv, wT, HIDD, NQKV);
  // 3. qkv = hb @ wT^T + b_qkv   (M=2048, N=9216, K=8192)
  gemm_bt_kernel<<<dim3(NQKV / 128, T_TOK / 128), 256, 0, stream>>>(hb, wT, b_qkv, qkv, T_TOK, NQKV, HIDD);
  // 4. cache init = input kv_cache
  copy_f32_kernel<<<(2 * 4096 * GG * DD / 4 + 255) / 256, 256, 0, stream>>>(kv_in, out_cache, 2 * 4096 * GG * DD / 4);
  // 5. rotary + split + cache scatter (new layouts)
  rotary_scatter_kernel<<<T_TOK, 256, 0, stream>>>(qkv, cosb, sinb, slots, qr, kr, vr, out_cache);
  // 6. w_dense (HID x HID) -> wT (reuse; serialized after GEMM1 by stream order)
  transpose_bf16_kernel<<<dim3(HIDD / 64, HIDD / 64), 256, 0, stream>>>(w_dense, wT, HIDD, HIDD);
  // 7. flash attention v2 -> attn bf16 (T, 8192)
  flash_attn_kernel<<<dim3(SS / 128, GG * HH, BB), 256, 0, stream>>>(qr, kr, vr, attn);
  // 8. out = attn @ wT^T + b_dense   (M=2048, N=8192, K=8192)
  gemm_bt_kernel<<<dim3(HIDD / 128, T_TOK / 128), 256, 0, stream>>>(attn, wT, b_dense, out, T_TOK, HIDD, HIDD);
}